// Round 7
// baseline (372.257 us; speedup 1.0000x reference)
//
#include <hip/hip_runtime.h>

// ---------------------------------------------------------------------------
// SimpleBiquadEQ: 10-band peaking-EQ cascade (IIR) over [32,2,262144] fp32.
// Round 9: 4 kernels, scan split by parallelism class.
//  Round-8 post-mortem: scan_mid (fold+KS+rewalk in one 64-WG kernel) spilled
//  (VGPR=256 cap, WRITE 65MB vs 21 ideal) and ran on 25% of CUs -> 149-218 us.
//  - pass_eq<false>: unchanged (validated): 4096 single-wave WGs, 16 KB tile,
//    global_load_lds, in-wave coefs -> SGPRs. Writes end-state T (transposed).
//  - scan_fold: 256 WGs x 128 thr, ONE group/thread (live ~70 VGPR, no spill),
//    per-WG prologue builds A^64, 8 Horner matvecs, writes gbuf (SoA planes,
//    coalesced).
//  - scan_ksrw: 64 WGs x 512 thr, ONE state/thread (validated r3 scan_ks
//    shape, ~64 live < 128 cap), prologue builds A^64 + 9 KS powers, KS over
//    LDS float2 SoA, then rewalk: 8 matvecs/thread, coalesced plane IO,
//    T := inclusive per-chunk prefixes in place.
//  - pass_eq<true>: unchanged; state init = read T[chunk-1].
// ---------------------------------------------------------------------------

#define B_   32
#define C_   2
#define S_   262144
#define NB   10
#define SEQ  64

#define F_LCH   64          // samples per chunk
#define F_PCH   4096        // chunks per sequence
#define F_G     8           // chunks per scan group
#define F_GRP   512         // groups per sequence

// T layout (float4 units): plane(seq,j,i) = ((seq*8 + j)*5 + i)*512, + g
// where chunk = 8*g + j.  Per seq: 40 planes x 512 float4 (5.24M floats total).
// gbuf layout (float4 units): (seq*5 + i)*512 + g   (SoA planes, coalesced)
#define T_FLOATS  5242880   // 64*40*512*4

// ===========================================================================
// shared matvec helper (M col-major in LDS: M[c*20+r]); acc += M*v
// ===========================================================================
__device__ __forceinline__ void matvec_acc(const float* M,
                                           const float* v, float* acc) {
  #pragma unroll
  for (int c = 0; c < 20; c++) {
    float vc = v[c];
    const float4* col = (const float4*)&M[c*20];
    float4 c0 = col[0], c1 = col[1], c2 = col[2], c3 = col[3], c4 = col[4];
    acc[0]  = fmaf(c0.x, vc, acc[0]);  acc[1]  = fmaf(c0.y, vc, acc[1]);
    acc[2]  = fmaf(c0.z, vc, acc[2]);  acc[3]  = fmaf(c0.w, vc, acc[3]);
    acc[4]  = fmaf(c1.x, vc, acc[4]);  acc[5]  = fmaf(c1.y, vc, acc[5]);
    acc[6]  = fmaf(c1.z, vc, acc[6]);  acc[7]  = fmaf(c1.w, vc, acc[7]);
    acc[8]  = fmaf(c2.x, vc, acc[8]);  acc[9]  = fmaf(c2.y, vc, acc[9]);
    acc[10] = fmaf(c2.z, vc, acc[10]); acc[11] = fmaf(c2.w, vc, acc[11]);
    acc[12] = fmaf(c3.x, vc, acc[12]); acc[13] = fmaf(c3.y, vc, acc[13]);
    acc[14] = fmaf(c3.z, vc, acc[14]); acc[15] = fmaf(c3.w, vc, acc[15]);
    acc[16] = fmaf(c4.x, vc, acc[16]); acc[17] = fmaf(c4.y, vc, acc[17]);
    acc[18] = fmaf(c4.z, vc, acc[18]); acc[19] = fmaf(c4.w, vc, acc[19]);
  }
}

// per-band RBJ peaking coefficients (normalized, na1 = -a1, na2 = -a2)
__device__ __forceinline__ void peak_coefs(float f, float g, float Q,
                                           float& c0, float& c1, float& c2,
                                           float& c3, float& c4) {
  float w0 = 6.28318530717958648f * f / 44100.0f;
  float sw = sinf(w0), cw = cosf(w0);
  float alpha = sw / (2.0f * Q);
  float A = expf(g * 0.05756462732485114f);   // 10^(g/40)
  float aA = alpha * A, adA = alpha / A;
  float inv = 1.0f / (1.0f + adA);
  c0 = (1.0f + aA) * inv;
  c1 = -2.0f * cw * inv;
  c2 = (1.0f - aA) * inv;
  c3 = 2.0f * cw * inv;      // -a1
  c4 = -(1.0f - adA) * inv;  // -a2
}

// ===========================================================================
// passes: 1 wave per wg, one 16 KB tile, coefs computed in-wave -> SGPRs.
// (unchanged from validated round 8)
// ===========================================================================
template <bool WRITE_OUT>
__global__ __launch_bounds__(64) void pass_eq(
    const float* __restrict__ x,
    const float* __restrict__ freqs, const float* __restrict__ gains,
    const float* __restrict__ qs,
    float* __restrict__ t, float* __restrict__ out) {
  __shared__ __align__(16) float4 smem[1024];   // 16 KB tile
  const int seq = blockIdx.y;
  const int b = seq >> 1;
  const int lane = threadIdx.x;
  const int tile = blockIdx.x;               // 0..63
  const int chunk = tile * F_LCH + lane;     // seq-local chunk id
  const float* xseq = x + (size_t)seq * S_;

  // ---- stage tile: pre-swizzled global source, linear LDS dest ----
  const float4* gx = (const float4*)(xseq + (size_t)tile * 4096);
  #pragma unroll
  for (int it = 0; it < 16; it++) {
    const int f = it * 64 + lane;
    const int c = f >> 4;
    const int gi = (c << 4) | ((f & 15) ^ (c & 15));
    __builtin_amdgcn_global_load_lds(
        (const __attribute__((address_space(1))) void*)(gx + gi),
        (__attribute__((address_space(3))) void*)(smem + it * 64),
        16, 0, 0);
  }
  // ---- edge samples (x[-1], x[-2] of the tile) ----
  float2 pe = make_float2(0.f, 0.f);
  if (tile > 0) pe = *((const float2*)gx - 1);   // broadcast
  // ---- <true>: prefix state = T[chunk-1] (inclusive prefix of c-1) ----
  float4 st4[5];
  if constexpr (WRITE_OUT) {
    const int cm1 = (chunk > 0) ? chunk - 1 : 0;
    const int jj = cm1 & 7, gg = cm1 >> 3;
    const float4* sv = (const float4*)t + ((size_t)seq * 8 + jj) * 5 * 512 + gg;
    #pragma unroll
    for (int i = 0; i < 5; i++) st4[i] = sv[i * 512];
  }
  // ---- coefs in-wave: lane k<10 computes band k; readlane -> SGPRs ----
  float cc0 = 0.f, cc1 = 0.f, cc2 = 0.f, cc3 = 0.f, cc4 = 0.f;
  if (lane < NB) {
    int idx = b * NB + lane;
    peak_coefs(freqs[idx], gains[idx], qs[idx], cc0, cc1, cc2, cc3, cc4);
  }
  float b0[NB], b1[NB], b2[NB], na1[NB], na2[NB];
  #pragma unroll
  for (int k = 0; k < NB; k++) {
    b0[k]  = __uint_as_float(__builtin_amdgcn_readlane(__float_as_uint(cc0), k));
    b1[k]  = __uint_as_float(__builtin_amdgcn_readlane(__float_as_uint(cc1), k));
    b2[k]  = __uint_as_float(__builtin_amdgcn_readlane(__float_as_uint(cc2), k));
    na1[k] = __uint_as_float(__builtin_amdgcn_readlane(__float_as_uint(cc3), k));
    na2[k] = __uint_as_float(__builtin_amdgcn_readlane(__float_as_uint(cc4), k));
  }

  asm volatile("s_waitcnt vmcnt(0) lgkmcnt(0)" ::: "memory");
  __builtin_amdgcn_sched_barrier(0);

  // ---- init filter state ----
  float p[NB], q_[NB];
  if constexpr (WRITE_OUT) {
    const bool z = (chunk == 0);
    #pragma unroll
    for (int i = 0; i < 5; i++) {
      float4 a = st4[i];
      p[2*i]   = z ? 0.f : a.x;  q_[2*i]   = z ? 0.f : a.y;
      p[2*i+1] = z ? 0.f : a.z;  q_[2*i+1] = z ? 0.f : a.w;
    }
  } else {
    #pragma unroll
    for (int k = 0; k < NB; k++) { p[k] = 0.0f; q_[k] = 0.0f; }
  }
  // ---- x1/x2 init from neighbor chunk in LDS ----
  float x1, x2;
  if (lane == 0) {
    x1 = pe.y; x2 = pe.x;            // zeros when tile==0
  } else {
    float4 pv = smem[(lane-1)*16 + (15 ^ ((lane-1) & 15))];
    x2 = pv.z; x1 = pv.w;
  }
  // ---- filter: my chunk = lane, 16 float4 from LDS ----
  #pragma unroll 2
  for (int qq = 0; qq < 16; qq++) {
    const int slot = lane*16 + (qq ^ (lane & 15));
    float4 xv = smem[slot];
    float xin[4] = {xv.x, xv.y, xv.z, xv.w};
    float o[4];
    #pragma unroll
    for (int j = 0; j < 4; j++) {
      float u = xin[j], u1 = x1, u2 = x2;
      x2 = x1; x1 = xin[j];
      #pragma unroll
      for (int k = 0; k < NB; k++) {
        float v = fmaf(b0[k], u,
                  fmaf(b1[k], u1,
                  fmaf(b2[k], u2,
                  fmaf(na1[k], p[k], na2[k] * q_[k]))));
        u1 = p[k]; u2 = q_[k];
        q_[k] = p[k]; p[k] = v;
        u = v;
      }
      o[j] = u;
    }
    if (WRITE_OUT) smem[slot] = make_float4(o[0], o[1], o[2], o[3]);
  }
  if constexpr (WRITE_OUT) {
    asm volatile("" ::: "memory");   // keep ds_writes before store-phase reads
    float4* gy = (float4*)(out + (size_t)seq * S_ + (size_t)tile * 4096);
    #pragma unroll 4
    for (int it = 0; it < 16; it++) {
      int f = it * 64 + lane;
      int c = f >> 4, q = f & 15;
      gy[f] = smem[c*16 + (q ^ (c & 15))];
    }
  } else {
    // ---- T write (transposed planes) ----
    const int jj = chunk & 7, gg = chunk >> 3;
    float4* td = (float4*)t + ((size_t)seq * 8 + jj) * 5 * 512 + gg;
    td[0]    = make_float4(p[0], q_[0], p[1], q_[1]);
    td[512]  = make_float4(p[2], q_[2], p[3], q_[3]);
    td[1024] = make_float4(p[4], q_[4], p[5], q_[5]);
    td[1536] = make_float4(p[6], q_[6], p[7], q_[7]);
    td[2048] = make_float4(p[8], q_[8], p[9], q_[9]);
  }
}

// ===========================================================================
// scan_fold: 256 WGs x 128 thr, one group per thread.
//   prologue: coefs -> A -> A^64 (6 squarings) -> Msh col-major.
//   fold: s = 0; for j: s = A^64*s + T_j  (coalesced plane reads, prefetch).
//   write gbuf SoA plane: gbuf4[(seq*5 + i)*512 + g].
// ===========================================================================
__global__ __launch_bounds__(128) void scan_fold(
    const float* __restrict__ t,
    const float* __restrict__ freqs, const float* __restrict__ gains,
    const float* __restrict__ qs, float* __restrict__ gbuf) {
  __shared__ float bufA[400], bufB[400];
  __shared__ __align__(16) float Msh[400];
  __shared__ float cfs[NB * 5];
  const int seq = blockIdx.y, b = seq >> 1, tid = threadIdx.x;
  const int g = blockIdx.x * 128 + tid;   // 0..511

  for (int e = tid; e < 400; e += 128) bufA[e] = 0.0f;
  if (tid < NB) {
    int idx = b * NB + tid;
    float c0, c1, c2, c3, c4;
    peak_coefs(freqs[idx], gains[idx], qs[idx], c0, c1, c2, c3, c4);
    cfs[tid*5+0] = c0; cfs[tid*5+1] = c1; cfs[tid*5+2] = c2;
    cfs[tid*5+3] = c3; cfs[tid*5+4] = c4;
  }
  __syncthreads();
  if (tid < 20) {
    int c = tid;
    float rp = 0.0f;
    for (int k = 0; k < NB; k++) {
      float b0 = cfs[k*5+0], b1 = cfs[k*5+1], b2 = cfs[k*5+2];
      float na1 = cfs[k*5+3], na2 = cfs[k*5+4];
      float val = (k > 0) ? b0 * rp : 0.0f;
      if (k > 0) {
        if (c == 2*k-2) val += b1;
        if (c == 2*k-1) val += b2;
      }
      if (c == 2*k)   val += na1;
      if (c == 2*k+1) val += na2;
      bufA[2*k*20 + c] = val;
      rp = val;
      if (c == 2*k) bufA[(2*k+1)*20 + c] = 1.0f;
    }
  }
  __syncthreads();
  {
    float* cur = bufA;
    float* nxt = bufB;
    for (int j = 1; j <= 6; j++) {          // cur becomes A^64
      for (int e = tid; e < 400; e += 128) {
        int r = e / 20, c = e % 20;
        float acc = 0.0f;
        #pragma unroll
        for (int k = 0; k < 20; k++) acc = fmaf(cur[r*20+k], cur[k*20+c], acc);
        nxt[e] = acc;
      }
      __syncthreads();
      { float* t_ = cur; cur = nxt; nxt = t_; }
    }
    for (int e = tid; e < 400; e += 128)
      Msh[(e % 20) * 20 + e / 20] = cur[e];  // col-major
  }
  __syncthreads();

  // ---- fold ----
  const float4* tb = (const float4*)t + (size_t)seq * 40 * 512 + g;
  float s[20];
  #pragma unroll
  for (int r = 0; r < 20; r++) s[r] = 0.0f;
  float4 nx[5];
  #pragma unroll
  for (int i = 0; i < 5; i++) nx[i] = tb[i * 512];
  #pragma unroll 1
  for (int j = 0; j < F_G; j++) {
    float ns[20];
    #pragma unroll
    for (int i = 0; i < 5; i++) {
      float4 a = nx[i];
      ns[4*i] = a.x; ns[4*i+1] = a.y; ns[4*i+2] = a.z; ns[4*i+3] = a.w;
    }
    if (j < F_G - 1) {
      const float4* np = tb + (size_t)(j + 1) * 5 * 512;
      #pragma unroll
      for (int i = 0; i < 5; i++) nx[i] = np[i * 512];
    }
    matvec_acc(Msh, s, ns);
    #pragma unroll
    for (int r = 0; r < 20; r++) s[r] = ns[r];
  }
  float4* gw = (float4*)gbuf + (size_t)seq * 5 * 512 + g;
  gw[0]    = make_float4(s[0],  s[1],  s[2],  s[3]);
  gw[512]  = make_float4(s[4],  s[5],  s[6],  s[7]);
  gw[1024] = make_float4(s[8],  s[9],  s[10], s[11]);
  gw[1536] = make_float4(s[12], s[13], s[14], s[15]);
  gw[2048] = make_float4(s[16], s[17], s[18], s[19]);
}

// ===========================================================================
// scan_ksrw: 64 WGs x 512 thr, one group-state per thread (~64 live VGPR,
// safely under the 128 cap that 512-thread launch bounds impose).
//   prologue: coefs -> A -> 17 squarings; Msh = A^64, Ks[s] = A^(512*2^s).
//   KS: 9 steps over 512 totals (h2 float2 SoA in LDS).
//   rewalk: s = h2[g-1] (exclusive); for j: s = A^64*s + T_j; T_j := s.
// ===========================================================================
__global__ __launch_bounds__(512) void scan_ksrw(
    float* __restrict__ t, const float* __restrict__ gbuf,
    const float* __restrict__ freqs, const float* __restrict__ gains,
    const float* __restrict__ qs) {
  __shared__ float2 h2[10 * 512];                 // 40 KB
  __shared__ __align__(16) float Msh[400];        // A^64 col-major
  __shared__ __align__(16) float Ks[9][400];      // KS matrices col-major
  __shared__ float bufA[400], bufB[400];
  __shared__ float cfs[NB * 5];
  const int seq = blockIdx.x, b = seq >> 1, i = threadIdx.x;

  for (int e = i; e < 400; e += 512) bufA[e] = 0.0f;
  if (i < NB) {
    int idx = b * NB + i;
    float c0, c1, c2, c3, c4;
    peak_coefs(freqs[idx], gains[idx], qs[idx], c0, c1, c2, c3, c4);
    cfs[i*5+0] = c0; cfs[i*5+1] = c1; cfs[i*5+2] = c2;
    cfs[i*5+3] = c3; cfs[i*5+4] = c4;
  }
  __syncthreads();
  if (i < 20) {
    int c = i;
    float rp = 0.0f;
    for (int k = 0; k < NB; k++) {
      float b0 = cfs[k*5+0], b1 = cfs[k*5+1], b2 = cfs[k*5+2];
      float na1 = cfs[k*5+3], na2 = cfs[k*5+4];
      float val = (k > 0) ? b0 * rp : 0.0f;
      if (k > 0) {
        if (c == 2*k-2) val += b1;
        if (c == 2*k-1) val += b2;
      }
      if (c == 2*k)   val += na1;
      if (c == 2*k+1) val += na2;
      bufA[2*k*20 + c] = val;
      rp = val;
      if (c == 2*k) bufA[(2*k+1)*20 + c] = 1.0f;
    }
  }
  __syncthreads();
  {
    float* cur = bufA;
    float* nxt = bufB;
    for (int j = 1; j <= 17; j++) {
      for (int e = i; e < 400; e += 512) {
        int r = e / 20, c = e % 20;
        float acc = 0.0f;
        #pragma unroll
        for (int k = 0; k < 20; k++) acc = fmaf(cur[r*20+k], cur[k*20+c], acc);
        nxt[e] = acc;
      }
      __syncthreads();
      { float* t_ = cur; cur = nxt; nxt = t_; }
      float* dst = nullptr;
      if (j == 6) dst = Msh;
      else if (j >= 9) dst = Ks[j - 9];
      if (dst)
        for (int e = i; e < 400; e += 512)
          dst[(e % 20) * 20 + e / 20] = cur[e];   // col-major
    }
  }
  __syncthreads();

  // ---- load own group total (coalesced SoA planes) ----
  float own[20];
  {
    const float4* gv = (const float4*)gbuf + (size_t)seq * 5 * 512 + i;
    #pragma unroll
    for (int k = 0; k < 5; k++) {
      float4 a = gv[k * 512];
      own[4*k] = a.x; own[4*k+1] = a.y; own[4*k+2] = a.z; own[4*k+3] = a.w;
    }
  }
  #pragma unroll
  for (int r2 = 0; r2 < 10; r2++)
    h2[r2*512 + i] = make_float2(own[2*r2], own[2*r2+1]);
  __syncthreads();

  // ---- Kogge-Stone over 512 group totals ----
  #pragma unroll 1
  for (int st = 0; st < 9; st++) {
    const int d = 1 << st;
    const float* K = Ks[st];
    const bool doA = (i >= d);
    float nb[20];
    if (doA) {
      #pragma unroll
      for (int r2 = 0; r2 < 10; r2++) {
        float2 v = h2[r2*512 + i - d]; nb[2*r2] = v.x; nb[2*r2+1] = v.y;
      }
    }
    __syncthreads();               // all reads done before any write
    if (doA) {
      matvec_acc(K, nb, own);
      #pragma unroll
      for (int r2 = 0; r2 < 10; r2++)
        h2[r2*512 + i] = make_float2(own[2*r2], own[2*r2+1]);
    }
    __syncthreads();               // writes done before next step's reads
  }

  // ---- exclusive shift + rewalk (T := inclusive per-chunk prefixes) ----
  float s[20];
  if (i > 0) {
    #pragma unroll
    for (int r2 = 0; r2 < 10; r2++) {
      float2 v = h2[r2*512 + i - 1]; s[2*r2] = v.x; s[2*r2+1] = v.y;
    }
  } else {
    #pragma unroll
    for (int r = 0; r < 20; r++) s[r] = 0.0f;
  }
  float4* tw = (float4*)t + (size_t)seq * 40 * 512 + i;
  #pragma unroll 1
  for (int j = 0; j < F_G; j++) {
    float ns[20];
    #pragma unroll
    for (int ii = 0; ii < 5; ii++) {
      float4 a = tw[(size_t)(j*5 + ii) * 512];
      ns[4*ii] = a.x; ns[4*ii+1] = a.y; ns[4*ii+2] = a.z; ns[4*ii+3] = a.w;
    }
    matvec_acc(Msh, s, ns);
    #pragma unroll
    for (int r = 0; r < 20; r++) s[r] = ns[r];
    float4* wp = tw + (size_t)(j*5) * 512;
    wp[0]    = make_float4(s[0],  s[1],  s[2],  s[3]);
    wp[512]  = make_float4(s[4],  s[5],  s[6],  s[7]);
    wp[1024] = make_float4(s[8],  s[9],  s[10], s[11]);
    wp[1536] = make_float4(s[12], s[13], s[14], s[15]);
    wp[2048] = make_float4(s[16], s[17], s[18], s[19]);
  }
}

// ===========================================================================
extern "C" void kernel_launch(void* const* d_in, const int* in_sizes, int n_in,
                              void* d_out, int out_size, void* d_ws, size_t ws_size,
                              hipStream_t stream) {
  const float* audio = (const float*)d_in[0];
  const float* freqs = (const float*)d_in[1];
  const float* gains = (const float*)d_in[2];
  const float* qs    = (const float*)d_in[3];
  float* out  = (float*)d_out;
  float* t    = (float*)d_ws;              // 21 MB
  float* gbuf = (float*)d_ws + T_FLOATS;   // 2.6 MB

  hipLaunchKernelGGL((pass_eq<false>), dim3(F_PCH / F_LCH, SEQ), dim3(64), 0,
                     stream, audio, freqs, gains, qs, t, (float*)nullptr);
  hipLaunchKernelGGL(scan_fold, dim3(F_GRP / 128, SEQ), dim3(128), 0, stream,
                     t, freqs, gains, qs, gbuf);
  hipLaunchKernelGGL(scan_ksrw, dim3(SEQ), dim3(512), 0, stream,
                     t, gbuf, freqs, gains, qs);
  hipLaunchKernelGGL((pass_eq<true>), dim3(F_PCH / F_LCH, SEQ), dim3(64), 0,
                     stream, audio, freqs, gains, qs, t, out);
}

// Round 8
// 232.686 us; speedup vs baseline: 1.5998x; 1.5998x over previous
//
#include <hip/hip_runtime.h>

// ---------------------------------------------------------------------------
// SimpleBiquadEQ: 10-band peaking-EQ cascade (IIR) over [32,2,262144] fp32.
// Round 10: 5 kernels, every shape chosen to be spill-free (the r7/r8/r9
// post-mortems: any multi-phase kernel holding several 20-float states spills
// at its block-size VGPR cap; each spill cost 100+ us).
//  - pass_eq<false/true>: unchanged (validated r8/r9): 4096 single-wave WGs,
//    16 KB tile, global_load_lds, in-wave coefs -> SGPRs.
//  - scan_fold: unchanged verbatim r9 (128 thr, A^64 prologue, no spill).
//  - scan_ks2: KS ONLY, 512 thr. Neighbor state read DIRECTLY from LDS inside
//    the accumulate (no nb[20] array; live ~30 VGPR). 2 barriers/step.
//    Writes exclusive group prefixes to sbuf (SoA planes).
//  - scan_rewalk: 128 thr x (4,64) WGs (r6-validated horner<true> shape +
//    6-squaring prologue): s = sbuf[g]; 8 Horner matvecs; T := inclusive
//    per-chunk prefixes in place.
// ---------------------------------------------------------------------------

#define B_   32
#define C_   2
#define S_   262144
#define NB   10
#define SEQ  64

#define F_LCH   64          // samples per chunk
#define F_PCH   4096        // chunks per sequence
#define F_G     8           // chunks per scan group
#define F_GRP   512         // groups per sequence

// T layout (float4 units): plane(seq,j,i) = ((seq*8 + j)*5 + i)*512, + g
// where chunk = 8*g + j.
// gbuf/sbuf layout (float4 units): (seq*5 + i)*512 + g (SoA planes)
#define T_FLOATS  5242880   // 64*40*512*4
#define G_FLOATS  655360    // 64*5*512*4

// ===========================================================================
// shared matvec helper (M col-major in LDS: M[c*20+r]); acc += M*v
// ===========================================================================
__device__ __forceinline__ void matvec_acc(const float* M,
                                           const float* v, float* acc) {
  #pragma unroll
  for (int c = 0; c < 20; c++) {
    float vc = v[c];
    const float4* col = (const float4*)&M[c*20];
    float4 c0 = col[0], c1 = col[1], c2 = col[2], c3 = col[3], c4 = col[4];
    acc[0]  = fmaf(c0.x, vc, acc[0]);  acc[1]  = fmaf(c0.y, vc, acc[1]);
    acc[2]  = fmaf(c0.z, vc, acc[2]);  acc[3]  = fmaf(c0.w, vc, acc[3]);
    acc[4]  = fmaf(c1.x, vc, acc[4]);  acc[5]  = fmaf(c1.y, vc, acc[5]);
    acc[6]  = fmaf(c1.z, vc, acc[6]);  acc[7]  = fmaf(c1.w, vc, acc[7]);
    acc[8]  = fmaf(c2.x, vc, acc[8]);  acc[9]  = fmaf(c2.y, vc, acc[9]);
    acc[10] = fmaf(c2.z, vc, acc[10]); acc[11] = fmaf(c2.w, vc, acc[11]);
    acc[12] = fmaf(c3.x, vc, acc[12]); acc[13] = fmaf(c3.y, vc, acc[13]);
    acc[14] = fmaf(c3.z, vc, acc[14]); acc[15] = fmaf(c3.w, vc, acc[15]);
    acc[16] = fmaf(c4.x, vc, acc[16]); acc[17] = fmaf(c4.y, vc, acc[17]);
    acc[18] = fmaf(c4.z, vc, acc[18]); acc[19] = fmaf(c4.w, vc, acc[19]);
  }
}

// per-band RBJ peaking coefficients (normalized, na1 = -a1, na2 = -a2)
__device__ __forceinline__ void peak_coefs(float f, float g, float Q,
                                           float& c0, float& c1, float& c2,
                                           float& c3, float& c4) {
  float w0 = 6.28318530717958648f * f / 44100.0f;
  float sw = sinf(w0), cw = cosf(w0);
  float alpha = sw / (2.0f * Q);
  float A = expf(g * 0.05756462732485114f);   // 10^(g/40)
  float aA = alpha * A, adA = alpha / A;
  float inv = 1.0f / (1.0f + adA);
  c0 = (1.0f + aA) * inv;
  c1 = -2.0f * cw * inv;
  c2 = (1.0f - aA) * inv;
  c3 = 2.0f * cw * inv;      // -a1
  c4 = -(1.0f - adA) * inv;  // -a2
}

// build A into bufA (400 floats, row-major) -- caller must sync before/after
__device__ __forceinline__ void build_A(const float* cfs, float* bufA,
                                        int tid) {
  if (tid < 20) {
    int c = tid;
    float rp = 0.0f;
    for (int k = 0; k < NB; k++) {
      float b0 = cfs[k*5+0], b1 = cfs[k*5+1], b2 = cfs[k*5+2];
      float na1 = cfs[k*5+3], na2 = cfs[k*5+4];
      float val = (k > 0) ? b0 * rp : 0.0f;
      if (k > 0) {
        if (c == 2*k-2) val += b1;
        if (c == 2*k-1) val += b2;
      }
      if (c == 2*k)   val += na1;
      if (c == 2*k+1) val += na2;
      bufA[2*k*20 + c] = val;
      rp = val;
      if (c == 2*k) bufA[(2*k+1)*20 + c] = 1.0f;
    }
  }
}

// ===========================================================================
// passes: 1 wave per wg, one 16 KB tile, coefs computed in-wave -> SGPRs.
// (unchanged from validated rounds 8/9)
// ===========================================================================
template <bool WRITE_OUT>
__global__ __launch_bounds__(64) void pass_eq(
    const float* __restrict__ x,
    const float* __restrict__ freqs, const float* __restrict__ gains,
    const float* __restrict__ qs,
    float* __restrict__ t, float* __restrict__ out) {
  __shared__ __align__(16) float4 smem[1024];   // 16 KB tile
  const int seq = blockIdx.y;
  const int b = seq >> 1;
  const int lane = threadIdx.x;
  const int tile = blockIdx.x;               // 0..63
  const int chunk = tile * F_LCH + lane;     // seq-local chunk id
  const float* xseq = x + (size_t)seq * S_;

  // ---- stage tile: pre-swizzled global source, linear LDS dest ----
  const float4* gx = (const float4*)(xseq + (size_t)tile * 4096);
  #pragma unroll
  for (int it = 0; it < 16; it++) {
    const int f = it * 64 + lane;
    const int c = f >> 4;
    const int gi = (c << 4) | ((f & 15) ^ (c & 15));
    __builtin_amdgcn_global_load_lds(
        (const __attribute__((address_space(1))) void*)(gx + gi),
        (__attribute__((address_space(3))) void*)(smem + it * 64),
        16, 0, 0);
  }
  // ---- edge samples (x[-1], x[-2] of the tile) ----
  float2 pe = make_float2(0.f, 0.f);
  if (tile > 0) pe = *((const float2*)gx - 1);   // broadcast
  // ---- <true>: prefix state = T[chunk-1] (inclusive prefix of c-1) ----
  float4 st4[5];
  if constexpr (WRITE_OUT) {
    const int cm1 = (chunk > 0) ? chunk - 1 : 0;
    const int jj = cm1 & 7, gg = cm1 >> 3;
    const float4* sv = (const float4*)t + ((size_t)seq * 8 + jj) * 5 * 512 + gg;
    #pragma unroll
    for (int i = 0; i < 5; i++) st4[i] = sv[i * 512];
  }
  // ---- coefs in-wave: lane k<10 computes band k; readlane -> SGPRs ----
  float cc0 = 0.f, cc1 = 0.f, cc2 = 0.f, cc3 = 0.f, cc4 = 0.f;
  if (lane < NB) {
    int idx = b * NB + lane;
    peak_coefs(freqs[idx], gains[idx], qs[idx], cc0, cc1, cc2, cc3, cc4);
  }
  float b0[NB], b1[NB], b2[NB], na1[NB], na2[NB];
  #pragma unroll
  for (int k = 0; k < NB; k++) {
    b0[k]  = __uint_as_float(__builtin_amdgcn_readlane(__float_as_uint(cc0), k));
    b1[k]  = __uint_as_float(__builtin_amdgcn_readlane(__float_as_uint(cc1), k));
    b2[k]  = __uint_as_float(__builtin_amdgcn_readlane(__float_as_uint(cc2), k));
    na1[k] = __uint_as_float(__builtin_amdgcn_readlane(__float_as_uint(cc3), k));
    na2[k] = __uint_as_float(__builtin_amdgcn_readlane(__float_as_uint(cc4), k));
  }

  asm volatile("s_waitcnt vmcnt(0) lgkmcnt(0)" ::: "memory");
  __builtin_amdgcn_sched_barrier(0);

  // ---- init filter state ----
  float p[NB], q_[NB];
  if constexpr (WRITE_OUT) {
    const bool z = (chunk == 0);
    #pragma unroll
    for (int i = 0; i < 5; i++) {
      float4 a = st4[i];
      p[2*i]   = z ? 0.f : a.x;  q_[2*i]   = z ? 0.f : a.y;
      p[2*i+1] = z ? 0.f : a.z;  q_[2*i+1] = z ? 0.f : a.w;
    }
  } else {
    #pragma unroll
    for (int k = 0; k < NB; k++) { p[k] = 0.0f; q_[k] = 0.0f; }
  }
  // ---- x1/x2 init from neighbor chunk in LDS ----
  float x1, x2;
  if (lane == 0) {
    x1 = pe.y; x2 = pe.x;            // zeros when tile==0
  } else {
    float4 pv = smem[(lane-1)*16 + (15 ^ ((lane-1) & 15))];
    x2 = pv.z; x1 = pv.w;
  }
  // ---- filter: my chunk = lane, 16 float4 from LDS ----
  #pragma unroll 2
  for (int qq = 0; qq < 16; qq++) {
    const int slot = lane*16 + (qq ^ (lane & 15));
    float4 xv = smem[slot];
    float xin[4] = {xv.x, xv.y, xv.z, xv.w};
    float o[4];
    #pragma unroll
    for (int j = 0; j < 4; j++) {
      float u = xin[j], u1 = x1, u2 = x2;
      x2 = x1; x1 = xin[j];
      #pragma unroll
      for (int k = 0; k < NB; k++) {
        float v = fmaf(b0[k], u,
                  fmaf(b1[k], u1,
                  fmaf(b2[k], u2,
                  fmaf(na1[k], p[k], na2[k] * q_[k]))));
        u1 = p[k]; u2 = q_[k];
        q_[k] = p[k]; p[k] = v;
        u = v;
      }
      o[j] = u;
    }
    if (WRITE_OUT) smem[slot] = make_float4(o[0], o[1], o[2], o[3]);
  }
  if constexpr (WRITE_OUT) {
    asm volatile("" ::: "memory");   // keep ds_writes before store-phase reads
    float4* gy = (float4*)(out + (size_t)seq * S_ + (size_t)tile * 4096);
    #pragma unroll 4
    for (int it = 0; it < 16; it++) {
      int f = it * 64 + lane;
      int c = f >> 4, q = f & 15;
      gy[f] = smem[c*16 + (q ^ (c & 15))];
    }
  } else {
    // ---- T write (transposed planes) ----
    const int jj = chunk & 7, gg = chunk >> 3;
    float4* td = (float4*)t + ((size_t)seq * 8 + jj) * 5 * 512 + gg;
    td[0]    = make_float4(p[0], q_[0], p[1], q_[1]);
    td[512]  = make_float4(p[2], q_[2], p[3], q_[3]);
    td[1024] = make_float4(p[4], q_[4], p[5], q_[5]);
    td[1536] = make_float4(p[6], q_[6], p[7], q_[7]);
    td[2048] = make_float4(p[8], q_[8], p[9], q_[9]);
  }
}

// ===========================================================================
// scan_fold: 256 WGs x 128 thr, one group per thread (verbatim r9, validated)
// ===========================================================================
__global__ __launch_bounds__(128) void scan_fold(
    const float* __restrict__ t,
    const float* __restrict__ freqs, const float* __restrict__ gains,
    const float* __restrict__ qs, float* __restrict__ gbuf) {
  __shared__ float bufA[400], bufB[400];
  __shared__ __align__(16) float Msh[400];
  __shared__ float cfs[NB * 5];
  const int seq = blockIdx.y, b = seq >> 1, tid = threadIdx.x;
  const int g = blockIdx.x * 128 + tid;   // 0..511

  for (int e = tid; e < 400; e += 128) bufA[e] = 0.0f;
  if (tid < NB) {
    int idx = b * NB + tid;
    float c0, c1, c2, c3, c4;
    peak_coefs(freqs[idx], gains[idx], qs[idx], c0, c1, c2, c3, c4);
    cfs[tid*5+0] = c0; cfs[tid*5+1] = c1; cfs[tid*5+2] = c2;
    cfs[tid*5+3] = c3; cfs[tid*5+4] = c4;
  }
  __syncthreads();
  build_A(cfs, bufA, tid);
  __syncthreads();
  {
    float* cur = bufA;
    float* nxt = bufB;
    for (int j = 1; j <= 6; j++) {          // cur becomes A^64
      for (int e = tid; e < 400; e += 128) {
        int r = e / 20, c = e % 20;
        float acc = 0.0f;
        #pragma unroll
        for (int k = 0; k < 20; k++) acc = fmaf(cur[r*20+k], cur[k*20+c], acc);
        nxt[e] = acc;
      }
      __syncthreads();
      { float* t_ = cur; cur = nxt; nxt = t_; }
    }
    for (int e = tid; e < 400; e += 128)
      Msh[(e % 20) * 20 + e / 20] = cur[e];  // col-major
  }
  __syncthreads();

  // ---- fold ----
  const float4* tb = (const float4*)t + (size_t)seq * 40 * 512 + g;
  float s[20];
  #pragma unroll
  for (int r = 0; r < 20; r++) s[r] = 0.0f;
  float4 nx[5];
  #pragma unroll
  for (int i = 0; i < 5; i++) nx[i] = tb[i * 512];
  #pragma unroll 1
  for (int j = 0; j < F_G; j++) {
    float ns[20];
    #pragma unroll
    for (int i = 0; i < 5; i++) {
      float4 a = nx[i];
      ns[4*i] = a.x; ns[4*i+1] = a.y; ns[4*i+2] = a.z; ns[4*i+3] = a.w;
    }
    if (j < F_G - 1) {
      const float4* np = tb + (size_t)(j + 1) * 5 * 512;
      #pragma unroll
      for (int i = 0; i < 5; i++) nx[i] = np[i * 512];
    }
    matvec_acc(Msh, s, ns);
    #pragma unroll
    for (int r = 0; r < 20; r++) s[r] = ns[r];
  }
  float4* gw = (float4*)gbuf + (size_t)seq * 5 * 512 + g;
  gw[0]    = make_float4(s[0],  s[1],  s[2],  s[3]);
  gw[512]  = make_float4(s[4],  s[5],  s[6],  s[7]);
  gw[1024] = make_float4(s[8],  s[9],  s[10], s[11]);
  gw[1536] = make_float4(s[12], s[13], s[14], s[15]);
  gw[2048] = make_float4(s[16], s[17], s[18], s[19]);
}

// ===========================================================================
// scan_ks2: 64 WGs x 512 thr, KS ONLY. Neighbor state read directly from LDS
// inside the accumulate (live set = own[20] + float2; no spill at 128 cap).
// 2 barriers per step separate the read and write phases.
// Writes EXCLUSIVE group prefixes to sbuf (SoA planes).
// ===========================================================================
__global__ __launch_bounds__(512) void scan_ks2(
    const float* __restrict__ gbuf, float* __restrict__ sbuf,
    const float* __restrict__ freqs, const float* __restrict__ gains,
    const float* __restrict__ qs) {
  __shared__ float2 h2[10 * 512];                 // 40 KB
  __shared__ __align__(16) float Ks[9][400];      // KS matrices col-major
  __shared__ float bufA[400], bufB[400];
  __shared__ float cfs[NB * 5];
  const int seq = blockIdx.x, b = seq >> 1, i = threadIdx.x;

  for (int e = i; e < 400; e += 512) bufA[e] = 0.0f;
  if (i < NB) {
    int idx = b * NB + i;
    float c0, c1, c2, c3, c4;
    peak_coefs(freqs[idx], gains[idx], qs[idx], c0, c1, c2, c3, c4);
    cfs[i*5+0] = c0; cfs[i*5+1] = c1; cfs[i*5+2] = c2;
    cfs[i*5+3] = c3; cfs[i*5+4] = c4;
  }
  __syncthreads();
  build_A(cfs, bufA, i);
  __syncthreads();
  {
    float* cur = bufA;
    float* nxt = bufB;
    for (int j = 1; j <= 17; j++) {
      for (int e = i; e < 400; e += 512) {
        int r = e / 20, c = e % 20;
        float acc = 0.0f;
        #pragma unroll
        for (int k = 0; k < 20; k++) acc = fmaf(cur[r*20+k], cur[k*20+c], acc);
        nxt[e] = acc;
      }
      __syncthreads();
      { float* t_ = cur; cur = nxt; nxt = t_; }
      if (j >= 9) {
        float* dst = Ks[j - 9];                   // A^(512*2^(j-9))
        for (int e = i; e < 400; e += 512)
          dst[(e % 20) * 20 + e / 20] = cur[e];   // col-major
      }
    }
  }
  __syncthreads();

  // ---- load own group total (coalesced SoA planes) -> h2 ----
  float own[20];
  {
    const float4* gv = (const float4*)gbuf + (size_t)seq * 5 * 512 + i;
    #pragma unroll
    for (int k = 0; k < 5; k++) {
      float4 a = gv[k * 512];
      own[4*k] = a.x; own[4*k+1] = a.y; own[4*k+2] = a.z; own[4*k+3] = a.w;
    }
  }
  #pragma unroll
  for (int r2 = 0; r2 < 10; r2++)
    h2[r2*512 + i] = make_float2(own[2*r2], own[2*r2+1]);
  __syncthreads();

  // ---- Kogge-Stone: read phase (LDS-direct acc) / barrier / write phase ----
  #pragma unroll 1
  for (int st = 0; st < 9; st++) {
    const int d = 1 << st;
    const float* K = Ks[st];
    if (i >= d) {
      #pragma unroll
      for (int r2 = 0; r2 < 10; r2++) {
        float2 v = h2[r2*512 + (i - d)];
        const float* col0 = &K[(2*r2)*20];
        const float* col1 = &K[(2*r2+1)*20];
        #pragma unroll
        for (int r = 0; r < 20; r++)
          own[r] = fmaf(col0[r], v.x, fmaf(col1[r], v.y, own[r]));
      }
    }
    __syncthreads();               // all reads done before any write
    if (i >= d) {
      #pragma unroll
      for (int r2 = 0; r2 < 10; r2++)
        h2[r2*512 + i] = make_float2(own[2*r2], own[2*r2+1]);
    }
    __syncthreads();               // writes done before next step's reads
  }

  // ---- exclusive shift -> sbuf (SoA planes) ----
  float4* sw = (float4*)sbuf + (size_t)seq * 5 * 512 + i;
  if (i > 0) {
    #pragma unroll
    for (int k = 0; k < 5; k++) {
      float2 a = h2[(2*k)*512 + i - 1];
      float2 c = h2[(2*k+1)*512 + i - 1];
      sw[k * 512] = make_float4(a.x, a.y, c.x, c.y);
    }
  } else {
    #pragma unroll
    for (int k = 0; k < 5; k++) sw[k * 512] = make_float4(0.f, 0.f, 0.f, 0.f);
  }
}

// ===========================================================================
// scan_rewalk: 256 WGs x 128 thr, one group per thread (r6-validated shape).
//   prologue: A -> A^64 -> Msh col-major.
//   s = sbuf[g] (exclusive); for j: s = A^64*s + T_j; T_j := s (inclusive).
// ===========================================================================
__global__ __launch_bounds__(128) void scan_rewalk(
    float* __restrict__ t, const float* __restrict__ sbuf,
    const float* __restrict__ freqs, const float* __restrict__ gains,
    const float* __restrict__ qs) {
  __shared__ float bufA[400], bufB[400];
  __shared__ __align__(16) float Msh[400];
  __shared__ float cfs[NB * 5];
  const int seq = blockIdx.y, b = seq >> 1, tid = threadIdx.x;
  const int g = blockIdx.x * 128 + tid;   // 0..511

  for (int e = tid; e < 400; e += 128) bufA[e] = 0.0f;
  if (tid < NB) {
    int idx = b * NB + tid;
    float c0, c1, c2, c3, c4;
    peak_coefs(freqs[idx], gains[idx], qs[idx], c0, c1, c2, c3, c4);
    cfs[tid*5+0] = c0; cfs[tid*5+1] = c1; cfs[tid*5+2] = c2;
    cfs[tid*5+3] = c3; cfs[tid*5+4] = c4;
  }
  __syncthreads();
  build_A(cfs, bufA, tid);
  __syncthreads();
  {
    float* cur = bufA;
    float* nxt = bufB;
    for (int j = 1; j <= 6; j++) {          // cur becomes A^64
      for (int e = tid; e < 400; e += 128) {
        int r = e / 20, c = e % 20;
        float acc = 0.0f;
        #pragma unroll
        for (int k = 0; k < 20; k++) acc = fmaf(cur[r*20+k], cur[k*20+c], acc);
        nxt[e] = acc;
      }
      __syncthreads();
      { float* t_ = cur; cur = nxt; nxt = t_; }
    }
    for (int e = tid; e < 400; e += 128)
      Msh[(e % 20) * 20 + e / 20] = cur[e];  // col-major
  }
  __syncthreads();

  // ---- s = exclusive group prefix ----
  float s[20];
  {
    const float4* sv = (const float4*)sbuf + (size_t)seq * 5 * 512 + g;
    #pragma unroll
    for (int i = 0; i < 5; i++) {
      float4 a = sv[i * 512];
      s[4*i] = a.x; s[4*i+1] = a.y; s[4*i+2] = a.z; s[4*i+3] = a.w;
    }
  }
  // ---- rewalk with prefetch ----
  float4* tw = (float4*)t + (size_t)seq * 40 * 512 + g;
  float4 nx[5];
  #pragma unroll
  for (int i = 0; i < 5; i++) nx[i] = tw[i * 512];
  #pragma unroll 1
  for (int j = 0; j < F_G; j++) {
    float ns[20];
    #pragma unroll
    for (int i = 0; i < 5; i++) {
      float4 a = nx[i];
      ns[4*i] = a.x; ns[4*i+1] = a.y; ns[4*i+2] = a.z; ns[4*i+3] = a.w;
    }
    if (j < F_G - 1) {
      const float4* np = tw + (size_t)(j + 1) * 5 * 512;
      #pragma unroll
      for (int i = 0; i < 5; i++) nx[i] = np[i * 512];
    }
    matvec_acc(Msh, s, ns);
    #pragma unroll
    for (int r = 0; r < 20; r++) s[r] = ns[r];
    float4* wp = tw + (size_t)(j*5) * 512;
    wp[0]    = make_float4(s[0],  s[1],  s[2],  s[3]);
    wp[512]  = make_float4(s[4],  s[5],  s[6],  s[7]);
    wp[1024] = make_float4(s[8],  s[9],  s[10], s[11]);
    wp[1536] = make_float4(s[12], s[13], s[14], s[15]);
    wp[2048] = make_float4(s[16], s[17], s[18], s[19]);
  }
}

// ===========================================================================
extern "C" void kernel_launch(void* const* d_in, const int* in_sizes, int n_in,
                              void* d_out, int out_size, void* d_ws, size_t ws_size,
                              hipStream_t stream) {
  const float* audio = (const float*)d_in[0];
  const float* freqs = (const float*)d_in[1];
  const float* gains = (const float*)d_in[2];
  const float* qs    = (const float*)d_in[3];
  float* out  = (float*)d_out;
  float* t    = (float*)d_ws;                         // 21 MB
  float* gbuf = (float*)d_ws + T_FLOATS;              // 2.6 MB
  float* sbuf = (float*)d_ws + T_FLOATS + G_FLOATS;   // 2.6 MB

  hipLaunchKernelGGL((pass_eq<false>), dim3(F_PCH / F_LCH, SEQ), dim3(64), 0,
                     stream, audio, freqs, gains, qs, t, (float*)nullptr);
  hipLaunchKernelGGL(scan_fold, dim3(F_GRP / 128, SEQ), dim3(128), 0, stream,
                     t, freqs, gains, qs, gbuf);
  hipLaunchKernelGGL(scan_ks2, dim3(SEQ), dim3(512), 0, stream,
                     gbuf, sbuf, freqs, gains, qs);
  hipLaunchKernelGGL(scan_rewalk, dim3(F_GRP / 128, SEQ), dim3(128), 0, stream,
                     t, sbuf, freqs, gains, qs);
  hipLaunchKernelGGL((pass_eq<true>), dim3(F_PCH / F_LCH, SEQ), dim3(64), 0,
                     stream, audio, freqs, gains, qs, t, out);
}